// Round 5
// baseline (80.274 us; speedup 1.0000x reference)
//
#include <hip/hip_runtime.h>
#include <hip/hip_bf16.h>
#include <math.h>

#define EPS_F 1e-7f

constexpr int Bn = 128, Sn = 1024, Dn = 256, ATTn = 128, QDn = 128;
constexpr int Mn = Bn * Sn;          // 131072 rows
constexpr int BM = 64;               // rows per block
constexpr int NBLK = Mn / BM;        // 2048 blocks
constexpr int KSTEPS = Dn / 32;      // 8 MFMA k-steps
constexpr int NJ = ATTn / 16;        // 8 column fragments

typedef short short8 __attribute__((ext_vector_type(8)));
typedef float f32x4  __attribute__((ext_vector_type(4)));

// Exact truncation split: f = hi + r exactly (hi = top-16-bit float),
// lo = bf16_rne(r). A_hi*B_hi + A_hi*B_lo + A_lo*B_hi ~ 2^-17 relative.
__device__ inline void split_bf(float f, ushort& hi, ushort& lo) {
    uint fb = __float_as_uint(f);
    hi = (ushort)(fb >> 16);
    float hf = __uint_as_float(fb & 0xffff0000u);
    float lf = f - hf;                       // exact
    __hip_bfloat16 lb = __float2bfloat16(lf);
    __builtin_memcpy(&lo, &lb, 2);
}

__device__ inline float tanh_fast(float x) {
    float cx = fminf(9.0f, fmaxf(-9.0f, x));
    float e = __builtin_amdgcn_exp2f(cx * 2.8853900817779268f);  // e^{2x}
    return (e - 1.0f) * __builtin_amdgcn_rcpf(e + 1.0f);
}

// ---------------- ws layout (bytes) ----------------
// [0,512)              u (128 f32)
// [512,66048)          Bhi (8ks * 8j * 64lane * 8 bf16)
// [66048,131584)       Blo
// [131584,2228736)     P   (2048 blk * 256 d f32)
// [2228736,2236928)    den (2048 f32)

// Merged prep: block 0 computes u = W_u @ query; blocks 1..16 build the
// MFMA-B-fragment-ordered bf16 hi/lo copies of W.
// Fragment (ks,j): lane l holds col = 16j+(l&15), k = 32ks+(l>>4)*8+i.
__global__ __launch_bounds__(256) void k_prep(
    const float* __restrict__ Wu, const float* __restrict__ q,
    float* __restrict__ u,
    const float* __restrict__ W,
    ushort* __restrict__ Bhi, ushort* __restrict__ Blo)
{
    if (blockIdx.x == 0) {
        __shared__ float qs[QDn];
        int t = threadIdx.x;
        if (t < QDn) qs[t] = q[t];
        __syncthreads();
        if (t < ATTn) {
            float acc = 0.f;
            #pragma unroll 8
            for (int j = 0; j < QDn; ++j) acc += Wu[t * QDn + j] * qs[j];
            u[t] = acc;
        }
        return;
    }
    int gid  = (blockIdx.x - 1) * 256 + threadIdx.x;   // 0..4095
    int lane = gid & 63;
    int j    = (gid >> 6) & 7;
    int ks   = gid >> 9;
    int col  = j * 16 + (lane & 15);
    int kb   = ks * 32 + (lane >> 4) * 8;
    #pragma unroll
    for (int i = 0; i < 8; ++i) {
        float f = W[(size_t)(kb + i) * ATTn + col];
        ushort h, l;
        split_bf(f, h, l);
        size_t idx = (size_t)gid * 8 + i;
        Bhi[idx] = h; Blo[idx] = l;
    }
}

// Fused: scores (bf16-split MFMA, K=256, N=128) + partial weighted sums.
// 2 waves/block; wave w owns rows w*32..w*32+31 as two 16-row fragments.
// Key prefetch distance = 2 k-steps to cover HBM latency.
__global__ __launch_bounds__(128, 3) void k_scores(
    const float*  __restrict__ key,
    const ushort* __restrict__ Bhi, const ushort* __restrict__ Blo,
    const float*  __restrict__ bias, const float* __restrict__ u,
    const int*    __restrict__ mask,
    float* __restrict__ P, float* __restrict__ den)
{
    __shared__ float  es[BM];
    __shared__ float4 part[2][64];
    const int t    = threadIdx.x;      // 0..127
    const int lane = t & 63;
    const int w    = t >> 6;           // wave 0..1
    const int gb   = blockIdx.x;
    const int row0 = gb * BM;
    const int l15  = lane & 15;
    const int lg   = lane >> 4;

    f32x4 acc[2][NJ];
    #pragma unroll
    for (int rf = 0; rf < 2; ++rf)
        #pragma unroll
        for (int j = 0; j < NJ; ++j) acc[rf][j] = (f32x4){0.f, 0.f, 0.f, 0.f};

    const float* ab0 = key + (size_t)(row0 + w * 32 + l15) * Dn + lg * 8;
    const float* ab1 = ab0 + 16 * Dn;

    // 2-deep key prefetch ring: buf[stage][rf*2 + half]
    float4 buf[2][4];
    buf[0][0] = *(const float4*)(ab0);
    buf[0][1] = *(const float4*)(ab0 + 4);
    buf[0][2] = *(const float4*)(ab1);
    buf[0][3] = *(const float4*)(ab1 + 4);
    buf[1][0] = *(const float4*)(ab0 + 32);
    buf[1][1] = *(const float4*)(ab0 + 36);
    buf[1][2] = *(const float4*)(ab1 + 32);
    buf[1][3] = *(const float4*)(ab1 + 36);

    #pragma unroll
    for (int ks = 0; ks < KSTEPS; ++ks) {
        const int st = ks & 1;
        float4 c0 = buf[st][0], c1 = buf[st][1];
        float4 c2 = buf[st][2], c3 = buf[st][3];
        if (ks + 2 < KSTEPS) {
            buf[st][0] = *(const float4*)(ab0 + (ks + 2) * 32);
            buf[st][1] = *(const float4*)(ab0 + (ks + 2) * 32 + 4);
            buf[st][2] = *(const float4*)(ab1 + (ks + 2) * 32);
            buf[st][3] = *(const float4*)(ab1 + (ks + 2) * 32 + 4);
        }
        short8 ah[2], al[2];
        {
            float f0[8] = {c0.x, c0.y, c0.z, c0.w, c1.x, c1.y, c1.z, c1.w};
            float f1[8] = {c2.x, c2.y, c2.z, c2.w, c3.x, c3.y, c3.z, c3.w};
            #pragma unroll
            for (int i = 0; i < 8; ++i) {
                ushort h, l;
                split_bf(f0[i], h, l); ah[0][i] = (short)h; al[0][i] = (short)l;
                split_bf(f1[i], h, l); ah[1][i] = (short)h; al[1][i] = (short)l;
            }
        }
        #pragma unroll
        for (int j = 0; j < NJ; ++j) {
            const size_t boff = ((size_t)(ks * NJ + j) * 64 + lane) * 8;
            short8 bh = *(const short8*)(Bhi + boff);
            short8 bl = *(const short8*)(Blo + boff);
            #pragma unroll
            for (int rf = 0; rf < 2; ++rf) {
                acc[rf][j] = __builtin_amdgcn_mfma_f32_16x16x32_bf16(ah[rf], bh, acc[rf][j], 0, 0, 0);
                acc[rf][j] = __builtin_amdgcn_mfma_f32_16x16x32_bf16(ah[rf], bl, acc[rf][j], 0, 0, 0);
                acc[rf][j] = __builtin_amdgcn_mfma_f32_16x16x32_bf16(al[rf], bh, acc[rf][j], 0, 0, 0);
            }
        }
    }

    // Epilogue: s(row) = sum_col tanh(acc+bias)*u; e = exp(s)*mask.
    // C/D layout: col = 16j + l15, row(frag-local) = lg*4 + reg.
    #pragma unroll
    for (int rf = 0; rf < 2; ++rf) {
        float s4[4] = {0.f, 0.f, 0.f, 0.f};
        #pragma unroll
        for (int j = 0; j < NJ; ++j) {
            int col = j * 16 + l15;
            float bv = bias[col], uvv = u[col];
            #pragma unroll
            for (int reg = 0; reg < 4; ++reg)
                s4[reg] += tanh_fast(acc[rf][j][reg] + bv) * uvv;
        }
        #pragma unroll
        for (int reg = 0; reg < 4; ++reg) {
            float s = s4[reg];
            s += __shfl_xor(s, 1);
            s += __shfl_xor(s, 2);
            s += __shfl_xor(s, 4);
            s += __shfl_xor(s, 8);
            if (l15 == 0) {
                int rl = w * 32 + rf * 16 + lg * 4 + reg;
                es[rl] = __builtin_amdgcn_exp2f(s * 1.4426950408889634f)
                         * (float)mask[row0 + rl];
            }
        }
    }
    __syncthreads();

    // block-partial denominator
    if (t < 64) {
        float v = es[t];
        #pragma unroll
        for (int m = 1; m < 64; m <<= 1) v += __shfl_xor(v, m);
        if (t == 0) den[gb] = v;
    }

    // phase 2: P[d] = sum_s es[s]*key[row0+s][d]  (tile is L2-hot)
    const int dq = t & 63;          // float4 lane over d
    const int sc = t >> 6;          // s-chunk (32 rows each)
    const float4* key4 = (const float4*)(key + (size_t)row0 * Dn);
    float4 a2 = make_float4(0.f, 0.f, 0.f, 0.f);
    #pragma unroll 4
    for (int s2 = sc * 32; s2 < sc * 32 + 32; ++s2) {
        float wv  = es[s2];
        float4 kv = key4[(size_t)s2 * 64 + dq];
        a2.x += wv * kv.x; a2.y += wv * kv.y;
        a2.z += wv * kv.z; a2.w += wv * kv.w;
    }
    part[sc][dq] = a2;
    __syncthreads();
    if (t < 64) {
        float4 p0 = part[0][t];
        float4 p1 = part[1][t];
        p0.x += p1.x; p0.y += p1.y; p0.z += p1.z; p0.w += p1.w;
        *(float4*)(P + (size_t)gb * Dn + t * 4) = p0;
    }
}

// combine 16 block-partials per batch, normalize.
__global__ __launch_bounds__(256) void k_final(const float* __restrict__ P,
        const float* __restrict__ den, float* __restrict__ out) {
    int b = blockIdx.x, t = threadIdx.x;
    float dtot = 0.f;
    #pragma unroll
    for (int k = 0; k < 16; ++k) dtot += den[b * 16 + k];
    float o = 0.f;
    #pragma unroll
    for (int k = 0; k < 16; ++k) o += P[(size_t)(b * 16 + k) * Dn + t];
    out[(size_t)b * Dn + t] = o / (dtot + EPS_F);
}

extern "C" void kernel_launch(void* const* d_in, const int* in_sizes, int n_in,
                              void* d_out, int out_size, void* d_ws, size_t ws_size,
                              hipStream_t stream) {
    const float* key   = (const float*)d_in[0];
    const float* query = (const float*)d_in[1];
    const int*   mask  = (const int*)d_in[2];
    const float* W     = (const float*)d_in[3];
    const float* bias  = (const float*)d_in[4];
    const float* Wu    = (const float*)d_in[5];
    float* out = (float*)d_out;

    char* ws = (char*)d_ws;
    float*  u   = (float*)(ws);
    ushort* Bhi = (ushort*)(ws + 512);
    ushort* Blo = (ushort*)(ws + 66048);
    float*  Pp  = (float*)(ws + 131584);
    float*  den = (float*)(ws + 2228736);

    hipLaunchKernelGGL(k_prep,   dim3(17),   dim3(256), 0, stream, Wu, query, u, W, Bhi, Blo);
    hipLaunchKernelGGL(k_scores, dim3(NBLK), dim3(128), 0, stream,
                       key, Bhi, Blo, bias, u, mask, Pp, den);
    hipLaunchKernelGGL(k_final,  dim3(Bn),   dim3(256), 0, stream, Pp, den, out);
}

// Round 6
// 63.710 us; speedup vs baseline: 1.2600x; 1.2600x over previous
//
#include <hip/hip_runtime.h>
#include <hip/hip_bf16.h>
#include <math.h>

#define EPS_F 1e-7f

constexpr int Bn = 128, Sn = 1024, Dn = 256, ATTn = 128, QDn = 128;
constexpr int Mn = Bn * Sn;          // 131072 rows
constexpr int BM = 128;              // rows per block
constexpr int NBLK = Mn / BM;        // 1024 blocks
constexpr int KSTEPS = Dn / 32;      // 8 MFMA k-steps
constexpr int NJ = ATTn / 16;        // 8 column fragments

typedef short short8 __attribute__((ext_vector_type(8)));
typedef float f32x4  __attribute__((ext_vector_type(4)));

// Exact truncation split: f = hi + r exactly (hi = top-16-bit float),
// lo = bf16_rne(r). A_hi*B_hi + A_hi*B_lo + A_lo*B_hi ~ 2^-17 relative.
__device__ inline void split_bf(float f, ushort& hi, ushort& lo) {
    uint fb = __float_as_uint(f);
    hi = (ushort)(fb >> 16);
    float hf = __uint_as_float(fb & 0xffff0000u);
    float lf = f - hf;                       // exact
    __hip_bfloat16 lb = __float2bfloat16(lf);
    __builtin_memcpy(&lo, &lb, 2);
}

__device__ inline float tanh_fast(float x) {
    float cx = fminf(9.0f, fmaxf(-9.0f, x));
    float e = __builtin_amdgcn_exp2f(cx * 2.8853900817779268f);  // e^{2x}
    return (e - 1.0f) * __builtin_amdgcn_rcpf(e + 1.0f);
}

// async global->LDS, 16B per lane. LDS dest is wave-uniform base + lane*16.
__device__ inline void gload_lds16(const float* g, void* lds_base) {
    __builtin_amdgcn_global_load_lds(
        (const __attribute__((address_space(1))) unsigned int*)g,
        (__attribute__((address_space(3))) unsigned int*)lds_base, 16, 0, 0);
}

// ---------------- ws layout (bytes) ----------------
// [0,512)              u (128 f32)
// [512,66048)          Bhi (8ks * 8j * 64lane * 8 bf16)
// [66048,131584)       Blo
// [131584,1180160)     P   (1024 blk * 256 d f32)
// [1180160,1184256)    den (1024 f32)

// Merged prep: block 0 computes u = W_u @ query; blocks 1..16 build the
// MFMA-B-fragment-ordered bf16 hi/lo copies of W.
// Fragment (ks,j): lane l holds col = 16j+(l&15), k = 32ks+(l>>4)*8+i.
__global__ __launch_bounds__(256) void k_prep(
    const float* __restrict__ Wu, const float* __restrict__ q,
    float* __restrict__ u,
    const float* __restrict__ W,
    ushort* __restrict__ Bhi, ushort* __restrict__ Blo)
{
    if (blockIdx.x == 0) {
        __shared__ float qs[QDn];
        int t = threadIdx.x;
        if (t < QDn) qs[t] = q[t];
        __syncthreads();
        if (t < ATTn) {
            float acc = 0.f;
            #pragma unroll 8
            for (int j = 0; j < QDn; ++j) acc += Wu[t * QDn + j] * qs[j];
            u[t] = acc;
        }
        return;
    }
    int gid  = (blockIdx.x - 1) * 256 + threadIdx.x;   // 0..4095
    int lane = gid & 63;
    int j    = (gid >> 6) & 7;
    int ks   = gid >> 9;
    int col  = j * 16 + (lane & 15);
    int kb   = ks * 32 + (lane >> 4) * 8;
    #pragma unroll
    for (int i = 0; i < 8; ++i) {
        float f = W[(size_t)(kb + i) * ATTn + col];
        ushort h, l;
        split_bf(f, h, l);
        size_t idx = (size_t)gid * 8 + i;
        Bhi[idx] = h; Blo[idx] = l;
    }
}

// Fused: scores (bf16-split MFMA, K=256, N=128) + partial weighted sums.
// A staged via global_load_lds (double-buffered LDS, 2-phase loop).
// LDS layout: 16B chunk (row, c) stored at slot row*8 + (c ^ (row&7)).
// global_load_lds writes linearly -> inverse-swizzle the per-lane SOURCE.
__global__ __launch_bounds__(256, 4) void k_scores(
    const float*  __restrict__ key,
    const ushort* __restrict__ Bhi, const ushort* __restrict__ Blo,
    const float*  __restrict__ bias, const float* __restrict__ u,
    const int*    __restrict__ mask,
    float* __restrict__ P, float* __restrict__ den)
{
    __shared__ float4 Atile[2][BM * 8];   // 2 x 16 KB
    __shared__ float  es[BM];
    __shared__ float4 part[4][64];

    const int t    = threadIdx.x;
    const int lane = t & 63;
    const int w    = t >> 6;
    const int gb   = blockIdx.x;
    const int row0 = gb * BM;
    const int l15  = lane & 15;
    const int lg   = lane >> 4;

    // Precompute per-thread staging source offsets (4 slots per thread).
    // slot s = i*256 + w*64 + lane; row = s>>3; cs = s&7; clogical = cs ^ (row&7)
    const float* gsrc[4];
    int sbase[4];
    #pragma unroll
    for (int i = 0; i < 4; ++i) {
        int s   = i * 256 + t;
        int row = s >> 3;
        int cs  = s & 7;
        int cl  = cs ^ (row & 7);
        gsrc[i]  = key + (size_t)(row0 + row) * Dn + cl * 4;
        sbase[i] = i * 256 + w * 64;          // wave-uniform LDS base (16B units)
    }

    f32x4 acc[2][NJ];
    #pragma unroll
    for (int rf = 0; rf < 2; ++rf)
        #pragma unroll
        for (int j = 0; j < NJ; ++j) acc[rf][j] = (f32x4){0.f, 0.f, 0.f, 0.f};

    // stage tile 0
    #pragma unroll
    for (int i = 0; i < 4; ++i)
        gload_lds16(gsrc[i], &Atile[0][sbase[i]]);
    __syncthreads();

    #pragma unroll
    for (int ks = 0; ks < KSTEPS; ++ks) {
        const int cur = ks & 1;
        if (ks + 1 < KSTEPS) {
            #pragma unroll
            for (int i = 0; i < 4; ++i)
                gload_lds16(gsrc[i] + (ks + 1) * 32, &Atile[cur ^ 1][sbase[i]]);
        }

        // A fragments from LDS (swizzled read)
        short8 ah[2], al[2];
        #pragma unroll
        for (int rf = 0; rf < 2; ++rf) {
            int row = w * 32 + rf * 16 + l15;
            float4 a0 = Atile[cur][row * 8 + ((lg * 2)     ^ (row & 7))];
            float4 a1 = Atile[cur][row * 8 + ((lg * 2 + 1) ^ (row & 7))];
            float f[8] = {a0.x, a0.y, a0.z, a0.w, a1.x, a1.y, a1.z, a1.w};
            #pragma unroll
            for (int i = 0; i < 8; ++i) {
                ushort h, l;
                split_bf(f[i], h, l);
                ah[rf][i] = (short)h; al[rf][i] = (short)l;
            }
        }

        // B with explicit j+1 register prefetch
        size_t boff = ((size_t)(ks * NJ) * 64 + lane) * 8;
        short8 bh = *(const short8*)(Bhi + boff);
        short8 bl = *(const short8*)(Blo + boff);
        #pragma unroll
        for (int j = 0; j < NJ; ++j) {
            short8 nbh, nbl;
            if (j + 1 < NJ) {
                size_t nb = ((size_t)(ks * NJ + j + 1) * 64 + lane) * 8;
                nbh = *(const short8*)(Bhi + nb);
                nbl = *(const short8*)(Blo + nb);
            }
            #pragma unroll
            for (int rf = 0; rf < 2; ++rf) {
                acc[rf][j] = __builtin_amdgcn_mfma_f32_16x16x32_bf16(ah[rf], bh, acc[rf][j], 0, 0, 0);
                acc[rf][j] = __builtin_amdgcn_mfma_f32_16x16x32_bf16(ah[rf], bl, acc[rf][j], 0, 0, 0);
                acc[rf][j] = __builtin_amdgcn_mfma_f32_16x16x32_bf16(al[rf], bh, acc[rf][j], 0, 0, 0);
            }
            bh = nbh; bl = nbl;
        }
        __syncthreads();   // drains stage loads (vmcnt 0) + protects cur buffer
    }

    // Epilogue: s(row) = sum_col tanh(acc+bias)*u; e = exp(s)*mask.
    // C/D layout: col = 16j + l15, row(frag-local) = lg*4 + reg.
    #pragma unroll
    for (int rf = 0; rf < 2; ++rf) {
        float s4[4] = {0.f, 0.f, 0.f, 0.f};
        #pragma unroll
        for (int j = 0; j < NJ; ++j) {
            int col = j * 16 + l15;
            float bv = bias[col], uvv = u[col];
            #pragma unroll
            for (int reg = 0; reg < 4; ++reg)
                s4[reg] += tanh_fast(acc[rf][j][reg] + bv) * uvv;
        }
        #pragma unroll
        for (int reg = 0; reg < 4; ++reg) {
            float s = s4[reg];
            s += __shfl_xor(s, 1);
            s += __shfl_xor(s, 2);
            s += __shfl_xor(s, 4);
            s += __shfl_xor(s, 8);
            if (l15 == 0) {
                int rl = w * 32 + rf * 16 + lg * 4 + reg;
                es[rl] = __builtin_amdgcn_exp2f(s * 1.4426950408889634f)
                         * (float)mask[row0 + rl];
            }
        }
    }
    __syncthreads();

    // block-partial denominator
    if (t < 64) {
        float v = es[t] + es[t + 64];
        #pragma unroll
        for (int m = 1; m < 64; m <<= 1) v += __shfl_xor(v, m);
        if (t == 0) den[gb] = v;
    }

    // phase 2: P[d] = sum_s es[s]*key[row0+s][d]  (tile is L2-hot)
    const int dq = t & 63;          // float4 lane over d
    const int sc = t >> 6;          // s-chunk (32 rows each)
    const float4* key4 = (const float4*)(key + (size_t)row0 * Dn);
    float4 a2 = make_float4(0.f, 0.f, 0.f, 0.f);
    #pragma unroll 4
    for (int s2 = sc * 32; s2 < sc * 32 + 32; ++s2) {
        float wv  = es[s2];
        float4 kv = key4[(size_t)s2 * 64 + dq];
        a2.x += wv * kv.x; a2.y += wv * kv.y;
        a2.z += wv * kv.z; a2.w += wv * kv.w;
    }
    part[sc][dq] = a2;
    __syncthreads();
    if (t < 64) {
        float4 o = part[0][t];
        #pragma unroll
        for (int c = 1; c < 4; ++c) {
            float4 p = part[c][t];
            o.x += p.x; o.y += p.y; o.z += p.z; o.w += p.w;
        }
        *(float4*)(P + (size_t)gb * Dn + t * 4) = o;
    }
}

// combine 8 block-partials per batch, normalize.
__global__ __launch_bounds__(256) void k_final(const float* __restrict__ P,
        const float* __restrict__ den, float* __restrict__ out) {
    int b = blockIdx.x, t = threadIdx.x;
    float dtot = 0.f;
    #pragma unroll
    for (int k = 0; k < 8; ++k) dtot += den[b * 8 + k];
    float o = 0.f;
    #pragma unroll
    for (int k = 0; k < 8; ++k) o += P[(size_t)(b * 8 + k) * Dn + t];
    out[(size_t)b * Dn + t] = o / (dtot + EPS_F);
}

extern "C" void kernel_launch(void* const* d_in, const int* in_sizes, int n_in,
                              void* d_out, int out_size, void* d_ws, size_t ws_size,
                              hipStream_t stream) {
    const float* key   = (const float*)d_in[0];
    const float* query = (const float*)d_in[1];
    const int*   mask  = (const int*)d_in[2];
    const float* W     = (const float*)d_in[3];
    const float* bias  = (const float*)d_in[4];
    const float* Wu    = (const float*)d_in[5];
    float* out = (float*)d_out;

    char* ws = (char*)d_ws;
    float*  u   = (float*)(ws);
    ushort* Bhi = (ushort*)(ws + 512);
    ushort* Blo = (ushort*)(ws + 66048);
    float*  Pp  = (float*)(ws + 131584);
    float*  den = (float*)(ws + 1180160);

    hipLaunchKernelGGL(k_prep,   dim3(17),   dim3(256), 0, stream, Wu, query, u, W, Bhi, Blo);
    hipLaunchKernelGGL(k_scores, dim3(NBLK), dim3(256), 0, stream,
                       key, Bhi, Blo, bias, u, mask, Pp, den);
    hipLaunchKernelGGL(k_final,  dim3(Bn),   dim3(256), 0, stream, Pp, den, out);
}

// Round 7
// 62.971 us; speedup vs baseline: 1.2748x; 1.0117x over previous
//
#include <hip/hip_runtime.h>
#include <hip/hip_bf16.h>
#include <math.h>

#define EPS_F 1e-7f

constexpr int Bn = 128, Sn = 1024, Dn = 256, ATTn = 128, QDn = 128;
constexpr int Mn = Bn * Sn;          // 131072 rows
constexpr int BM = 64;               // rows per block
constexpr int NBLK = Mn / BM;        // 2048 blocks
constexpr int KSTEPS = Dn / 32;      // 8 MFMA k-steps
constexpr int NJ = ATTn / 16;        // 8 column fragments

typedef short short8 __attribute__((ext_vector_type(8)));
typedef float f32x4  __attribute__((ext_vector_type(4)));

// Exact truncation split: f = hi + r exactly (hi = top-16-bit float),
// lo = bf16_rne(r). A_hi*B_hi + A_hi*B_lo + A_lo*B_hi ~ 2^-17 relative.
__device__ inline void split_bf(float f, ushort& hi, ushort& lo) {
    uint fb = __float_as_uint(f);
    hi = (ushort)(fb >> 16);
    float hf = __uint_as_float(fb & 0xffff0000u);
    float lf = f - hf;                       // exact
    __hip_bfloat16 lb = __float2bfloat16(lf);
    __builtin_memcpy(&lo, &lb, 2);
}

__device__ inline float tanh_fast(float x) {
    float cx = fminf(9.0f, fmaxf(-9.0f, x));
    float e = __builtin_amdgcn_exp2f(cx * 2.8853900817779268f);  // e^{2x}
    return (e - 1.0f) * __builtin_amdgcn_rcpf(e + 1.0f);
}

// async global->LDS, 16B per lane. LDS dest is wave-uniform base + lane*16.
__device__ inline void gload_lds16(const float* g, void* lds_base) {
    __builtin_amdgcn_global_load_lds(
        (const __attribute__((address_space(1))) unsigned int*)g,
        (__attribute__((address_space(3))) unsigned int*)lds_base, 16, 0, 0);
}

// ---------------- ws layout (bytes) ----------------
// [0,512)              u (128 f32)
// [512,66048)          Bhi (8ks * 8j * 64lane * 8 bf16)
// [66048,131584)       Blo
// [131584,2228736)     P   (2048 blk * 256 d f32)
// [2228736,2236928)    den (2048 f32)

// Merged prep: block 0 computes u = W_u @ query; blocks 1..16 build the
// MFMA-B-fragment-ordered bf16 hi/lo copies of W.
// Fragment (ks,j): lane l holds col = 16j+(l&15), k = 32ks+(l>>4)*8+i.
__global__ __launch_bounds__(256) void k_prep(
    const float* __restrict__ Wu, const float* __restrict__ q,
    float* __restrict__ u,
    const float* __restrict__ W,
    ushort* __restrict__ Bhi, ushort* __restrict__ Blo)
{
    if (blockIdx.x == 0) {
        __shared__ float qs[QDn];
        int t = threadIdx.x;
        if (t < QDn) qs[t] = q[t];
        __syncthreads();
        if (t < ATTn) {
            float acc = 0.f;
            #pragma unroll 8
            for (int j = 0; j < QDn; ++j) acc += Wu[t * QDn + j] * qs[j];
            u[t] = acc;
        }
        return;
    }
    int gid  = (blockIdx.x - 1) * 256 + threadIdx.x;   // 0..4095
    int lane = gid & 63;
    int j    = (gid >> 6) & 7;
    int ks   = gid >> 9;
    int col  = j * 16 + (lane & 15);
    int kb   = ks * 32 + (lane >> 4) * 8;
    #pragma unroll
    for (int i = 0; i < 8; ++i) {
        float f = W[(size_t)(kb + i) * ATTn + col];
        ushort h, l;
        split_bf(f, h, l);
        size_t idx = (size_t)gid * 8 + i;
        Bhi[idx] = h; Blo[idx] = l;
    }
}

// Fused: scores (bf16-split MFMA, K=256, N=128) + partial weighted sums.
// BM=64, 128 threads, 8 KB A-tile double-buffered via global_load_lds ->
// ~8 blocks/CU resident, each with an independent stage in flight (TLP).
// LDS layout: 16B chunk (row, c) stored at slot row*8 + (c ^ (row&7)).
// global_load_lds writes linearly -> inverse-swizzle the per-lane SOURCE.
__global__ __launch_bounds__(128, 4) void k_scores(
    const float*  __restrict__ key,
    const ushort* __restrict__ Bhi, const ushort* __restrict__ Blo,
    const float*  __restrict__ bias, const float* __restrict__ u,
    const int*    __restrict__ mask,
    float* __restrict__ P, float* __restrict__ den)
{
    __shared__ float4 Atile[2][BM * 8];   // 2 x 8 KB
    __shared__ float  es[BM];
    __shared__ float4 part[2][64];

    const int t    = threadIdx.x;      // 0..127
    const int lane = t & 63;
    const int w    = t >> 6;           // wave 0..1
    const int gb   = blockIdx.x;
    const int row0 = gb * BM;
    const int l15  = lane & 15;
    const int lg   = lane >> 4;

    // Per-thread staging source (4 slots per thread, 512 slots total).
    // slot s = i*128 + t; row = s>>3; cs = s&7; clogical = cs ^ (row&7).
    const float* gsrc[4];
    int sbase[4];
    #pragma unroll
    for (int i = 0; i < 4; ++i) {
        int s   = i * 128 + t;
        int row = s >> 3;
        int cs  = s & 7;
        int cl  = cs ^ (row & 7);
        gsrc[i]  = key + (size_t)(row0 + row) * Dn + cl * 4;
        sbase[i] = i * 128 + w * 64;          // wave-uniform LDS base (16B units)
    }

    f32x4 acc[2][NJ];
    #pragma unroll
    for (int rf = 0; rf < 2; ++rf)
        #pragma unroll
        for (int j = 0; j < NJ; ++j) acc[rf][j] = (f32x4){0.f, 0.f, 0.f, 0.f};

    // stage tile 0
    #pragma unroll
    for (int i = 0; i < 4; ++i)
        gload_lds16(gsrc[i], &Atile[0][sbase[i]]);
    __syncthreads();

    #pragma unroll
    for (int ks = 0; ks < KSTEPS; ++ks) {
        const int cur = ks & 1;
        if (ks + 1 < KSTEPS) {
            #pragma unroll
            for (int i = 0; i < 4; ++i)
                gload_lds16(gsrc[i] + (ks + 1) * 32, &Atile[cur ^ 1][sbase[i]]);
        }

        // A fragments from LDS (swizzled read)
        short8 ah[2], al[2];
        #pragma unroll
        for (int rf = 0; rf < 2; ++rf) {
            int row = w * 32 + rf * 16 + l15;
            float4 a0 = Atile[cur][row * 8 + ((lg * 2)     ^ (row & 7))];
            float4 a1 = Atile[cur][row * 8 + ((lg * 2 + 1) ^ (row & 7))];
            float f[8] = {a0.x, a0.y, a0.z, a0.w, a1.x, a1.y, a1.z, a1.w};
            #pragma unroll
            for (int i = 0; i < 8; ++i) {
                ushort h, l;
                split_bf(f[i], h, l);
                ah[rf][i] = (short)h; al[rf][i] = (short)l;
            }
        }

        // B with explicit j+1 register prefetch
        size_t boff = ((size_t)(ks * NJ) * 64 + lane) * 8;
        short8 bh = *(const short8*)(Bhi + boff);
        short8 bl = *(const short8*)(Blo + boff);
        #pragma unroll
        for (int j = 0; j < NJ; ++j) {
            short8 nbh, nbl;
            if (j + 1 < NJ) {
                size_t nb = ((size_t)(ks * NJ + j + 1) * 64 + lane) * 8;
                nbh = *(const short8*)(Bhi + nb);
                nbl = *(const short8*)(Blo + nb);
            }
            #pragma unroll
            for (int rf = 0; rf < 2; ++rf) {
                acc[rf][j] = __builtin_amdgcn_mfma_f32_16x16x32_bf16(ah[rf], bh, acc[rf][j], 0, 0, 0);
                acc[rf][j] = __builtin_amdgcn_mfma_f32_16x16x32_bf16(ah[rf], bl, acc[rf][j], 0, 0, 0);
                acc[rf][j] = __builtin_amdgcn_mfma_f32_16x16x32_bf16(al[rf], bh, acc[rf][j], 0, 0, 0);
            }
            bh = nbh; bl = nbl;
        }
        __syncthreads();   // drains stage loads + protects cur buffer
    }

    // Epilogue: s(row) = sum_col tanh(acc+bias)*u; e = exp(s)*mask.
    // C/D layout: col = 16j + l15, row(frag-local) = lg*4 + reg.
    #pragma unroll
    for (int rf = 0; rf < 2; ++rf) {
        float s4[4] = {0.f, 0.f, 0.f, 0.f};
        #pragma unroll
        for (int j = 0; j < NJ; ++j) {
            int col = j * 16 + l15;
            float bv = bias[col], uvv = u[col];
            #pragma unroll
            for (int reg = 0; reg < 4; ++reg)
                s4[reg] += tanh_fast(acc[rf][j][reg] + bv) * uvv;
        }
        #pragma unroll
        for (int reg = 0; reg < 4; ++reg) {
            float s = s4[reg];
            s += __shfl_xor(s, 1);
            s += __shfl_xor(s, 2);
            s += __shfl_xor(s, 4);
            s += __shfl_xor(s, 8);
            if (l15 == 0) {
                int rl = w * 32 + rf * 16 + lg * 4 + reg;
                es[rl] = __builtin_amdgcn_exp2f(s * 1.4426950408889634f)
                         * (float)mask[row0 + rl];
            }
        }
    }
    __syncthreads();

    // block-partial denominator
    if (t < 64) {
        float v = es[t];
        #pragma unroll
        for (int m = 1; m < 64; m <<= 1) v += __shfl_xor(v, m);
        if (t == 0) den[gb] = v;
    }

    // phase 2: P[d] = sum_s es[s]*key[row0+s][d]  (tile is L2-hot)
    const int dq = t & 63;          // float4 lane over d
    const int sc = t >> 6;          // s-chunk (32 rows each)
    const float4* key4 = (const float4*)(key + (size_t)row0 * Dn);
    float4 a2 = make_float4(0.f, 0.f, 0.f, 0.f);
    #pragma unroll 4
    for (int s2 = sc * 32; s2 < sc * 32 + 32; ++s2) {
        float wv  = es[s2];
        float4 kv = key4[(size_t)s2 * 64 + dq];
        a2.x += wv * kv.x; a2.y += wv * kv.y;
        a2.z += wv * kv.z; a2.w += wv * kv.w;
    }
    part[sc][dq] = a2;
    __syncthreads();
    if (t < 64) {
        float4 p0 = part[0][t];
        float4 p1 = part[1][t];
        p0.x += p1.x; p0.y += p1.y; p0.z += p1.z; p0.w += p1.w;
        *(float4*)(P + (size_t)gb * Dn + t * 4) = p0;
    }
}

// combine 16 block-partials per batch, normalize.
__global__ __launch_bounds__(256) void k_final(const float* __restrict__ P,
        const float* __restrict__ den, float* __restrict__ out) {
    int b = blockIdx.x, t = threadIdx.x;
    float dtot = 0.f;
    #pragma unroll
    for (int k = 0; k < 16; ++k) dtot += den[b * 16 + k];
    float o = 0.f;
    #pragma unroll
    for (int k = 0; k < 16; ++k) o += P[(size_t)(b * 16 + k) * Dn + t];
    out[(size_t)b * Dn + t] = o / (dtot + EPS_F);
}

extern "C" void kernel_launch(void* const* d_in, const int* in_sizes, int n_in,
                              void* d_out, int out_size, void* d_ws, size_t ws_size,
                              hipStream_t stream) {
    const float* key   = (const float*)d_in[0];
    const float* query = (const float*)d_in[1];
    const int*   mask  = (const int*)d_in[2];
    const float* W     = (const float*)d_in[3];
    const float* bias  = (const float*)d_in[4];
    const float* Wu    = (const float*)d_in[5];
    float* out = (float*)d_out;

    char* ws = (char*)d_ws;
    float*  u   = (float*)(ws);
    ushort* Bhi = (ushort*)(ws + 512);
    ushort* Blo = (ushort*)(ws + 66048);
    float*  Pp  = (float*)(ws + 131584);
    float*  den = (float*)(ws + 2228736);

    hipLaunchKernelGGL(k_prep,   dim3(17),   dim3(256), 0, stream, Wu, query, u, W, Bhi, Blo);
    hipLaunchKernelGGL(k_scores, dim3(NBLK), dim3(128), 0, stream,
                       key, Bhi, Blo, bias, u, mask, Pp, den);
    hipLaunchKernelGGL(k_final,  dim3(Bn),   dim3(256), 0, stream, Pp, den, out);
}

// Round 8
// 59.482 us; speedup vs baseline: 1.3496x; 1.0587x over previous
//
#include <hip/hip_runtime.h>
#include <hip/hip_bf16.h>
#include <math.h>

#define EPS_F 1e-7f

constexpr int Bn = 128, Sn = 1024, Dn = 256, ATTn = 128, QDn = 128;
constexpr int Mn = Bn * Sn;          // 131072 rows
constexpr int BM = 128;              // rows per block
constexpr int NBLK = Mn / BM;        // 1024 blocks
constexpr int NJ = ATTn / 16;        // 8 column fragments

typedef short short8 __attribute__((ext_vector_type(8)));
typedef float f32x4  __attribute__((ext_vector_type(4)));

// Exact truncation split: f = hi + r exactly (hi = top-16-bit float),
// lo = bf16_rne(r). A_hi*B_hi + A_hi*B_lo + A_lo*B_hi ~ 2^-17 relative.
__device__ inline void split_bf(float f, ushort& hi, ushort& lo) {
    uint fb = __float_as_uint(f);
    hi = (ushort)(fb >> 16);
    float hf = __uint_as_float(fb & 0xffff0000u);
    float lf = f - hf;                       // exact
    __hip_bfloat16 lb = __float2bfloat16(lf);
    __builtin_memcpy(&lo, &lb, 2);
}

__device__ inline float hi2f(short h) {
    return __uint_as_float(((uint)(ushort)h) << 16);
}

__device__ inline float tanh_fast(float x) {
    float cx = fminf(9.0f, fmaxf(-9.0f, x));
    float e = __builtin_amdgcn_exp2f(cx * 2.8853900817779268f);  // e^{2x}
    return (e - 1.0f) * __builtin_amdgcn_rcpf(e + 1.0f);
}

// async global->LDS, 16B per lane. LDS dest is wave-uniform base + lane*16.
__device__ inline void gload_lds16(const void* g, void* lds_base) {
    __builtin_amdgcn_global_load_lds(
        (const __attribute__((address_space(1))) unsigned int*)g,
        (__attribute__((address_space(3))) unsigned int*)lds_base, 16, 0, 0);
}

// ---------------- ws layout (bytes) ----------------
// [0,512)              u (128 f32)
// [512,66048)          Bhi (8ks * 8j * 64lane * 8 bf16)
// [66048,131584)       Blo
// [131584,1180160)     P   (1024 blk * 256 d f32)
// [1180160,1184256)    den (1024 f32)

// Merged prep: block 0 computes u = W_u @ query; blocks 1..16 build the
// MFMA-B-fragment-ordered bf16 hi/lo copies of W.
// Fragment (ks,j): lane l holds col = 16j+(l&15), k = 32ks+(l>>4)*8+i.
__global__ __launch_bounds__(256) void k_prep(
    const float* __restrict__ Wu, const float* __restrict__ q,
    float* __restrict__ u,
    const float* __restrict__ W,
    ushort* __restrict__ Bhi, ushort* __restrict__ Blo)
{
    if (blockIdx.x == 0) {
        __shared__ float qs[QDn];
        int t = threadIdx.x;
        if (t < QDn) qs[t] = q[t];
        __syncthreads();
        if (t < ATTn) {
            float acc = 0.f;
            #pragma unroll 8
            for (int j = 0; j < QDn; ++j) acc += Wu[t * QDn + j] * qs[j];
            u[t] = acc;
        }
        return;
    }
    int gid  = (blockIdx.x - 1) * 256 + threadIdx.x;   // 0..4095
    int lane = gid & 63;
    int j    = (gid >> 6) & 7;
    int ks   = gid >> 9;
    int col  = j * 16 + (lane & 15);
    int kb   = ks * 32 + (lane >> 4) * 8;
    #pragma unroll
    for (int i = 0; i < 8; ++i) {
        float f = W[(size_t)(kb + i) * ATTn + col];
        ushort h, l;
        split_bf(f, h, l);
        size_t idx = (size_t)gid * 8 + i;
        Bhi[idx] = h; Blo[idx] = l;
    }
}

#define MFMA_BF16 __builtin_amdgcn_mfma_f32_16x16x32_bf16

// One quarter-K (2 k-steps). B for this quarter already resident in
// buf[Q&1]; stages next quarter's B into buf[(Q+1)&1] at the top (hidden
// under this quarter's MFMAs), refills kv with next quarter's key after
// each conversion. One barrier at the end.
template<int Q>
__device__ __forceinline__ void process_quarter(
    char* smem, const float* kb0, const float* kb1,
    const ushort* __restrict__ Bhi, const ushort* __restrict__ Blo,
    int t, int w, int lane,
    float4 (&kv)[2][4], short8 (&ahk)[2][8], f32x4 (&acc)[2][NJ])
{
    const float4* Bcur = (const float4*)(smem + (Q & 1) * 32768);
    if (Q < 3) {   // stage next quarter's B (32 KB) into the other buffer
        char* Bnxt = smem + ((Q + 1) & 1) * 32768;
        #pragma unroll
        for (int i = 0; i < 8; ++i) {
            int c   = i * 256 + t;           // chunk = ks2<<10 | j<<7 | s<<6 | lane
            int cl  = c & 63;
            int cs  = (c >> 6) & 1;
            int cj  = (c >> 7) & 7;
            int ck2 = (c >> 10) & 1;
            int g   = ((Q + 1) * 2 + ck2) * 8 + cj;
            const ushort* src = (cs ? Blo : Bhi) + ((size_t)g * 64 + cl) * 8;
            gload_lds16(src, Bnxt + (i * 256 + w * 64) * 16);
        }
    }
    #pragma unroll
    for (int ks2 = 0; ks2 < 2; ++ks2) {
        // convert current kv -> bf16 hi (kept for phase 2) / lo (transient)
        short8 al[2];
        #pragma unroll
        for (int rf = 0; rf < 2; ++rf) {
            const float4 v0 = kv[rf][ks2 * 2], v1 = kv[rf][ks2 * 2 + 1];
            float f[8] = {v0.x, v0.y, v0.z, v0.w, v1.x, v1.y, v1.z, v1.w};
            #pragma unroll
            for (int i = 0; i < 8; ++i) {
                ushort h, l;
                split_bf(f[i], h, l);
                ahk[rf][Q * 2 + ks2][i] = (short)h;
                al[rf][i] = (short)l;
            }
        }
        // refill the just-consumed kv slots with next quarter's key
        if (Q < 3) {
            const int off = ((Q + 1) * 2 + ks2) * 32;
            kv[0][ks2 * 2]     = *(const float4*)(kb0 + off);
            kv[0][ks2 * 2 + 1] = *(const float4*)(kb0 + off + 4);
            kv[1][ks2 * 2]     = *(const float4*)(kb1 + off);
            kv[1][ks2 * 2 + 1] = *(const float4*)(kb1 + off + 4);
        }
        // MFMA over 8 column fragments, B from LDS with j+1 prefetch
        const int cb = (ks2 << 10) | lane;
        short8 bh = *(const short8*)&Bcur[cb];
        short8 bl = *(const short8*)&Bcur[cb + 64];
        #pragma unroll
        for (int j = 0; j < NJ; ++j) {
            short8 nbh, nbl;
            if (j + 1 < NJ) {
                nbh = *(const short8*)&Bcur[cb + ((j + 1) << 7)];
                nbl = *(const short8*)&Bcur[cb + ((j + 1) << 7) + 64];
            }
            #pragma unroll
            for (int rf = 0; rf < 2; ++rf) {
                acc[rf][j] = MFMA_BF16(ahk[rf][Q * 2 + ks2], bh, acc[rf][j], 0, 0, 0);
                acc[rf][j] = MFMA_BF16(ahk[rf][Q * 2 + ks2], bl, acc[rf][j], 0, 0, 0);
                acc[rf][j] = MFMA_BF16(al[rf], bh, acc[rf][j], 0, 0, 0);
            }
            bh = nbh; bl = nbl;
        }
    }
    __syncthreads();   // all waves done with Bcur; staged Bnxt + kv landed
}

// Fused: scores (bf16-split MFMA, K=256, N=128) + in-register weighted sums.
// 4 waves, 32 rows each (2 fragments). B double-buffered in LDS (2x32 KB),
// key -> registers in quarter bursts, phase 2 entirely from kept hi-frags.
__global__ __launch_bounds__(256, 2) void k_scores(
    const float*  __restrict__ key,
    const ushort* __restrict__ Bhi, const ushort* __restrict__ Blo,
    const float*  __restrict__ bias, const float* __restrict__ u,
    const int*    __restrict__ mask,
    float* __restrict__ P, float* __restrict__ den)
{
    __shared__ char smem[65536];   // 2 x 32 KB B buffers; es/part alias buf0 later
    float* es   = (float*)smem;          // [128], valid after all B use
    float* part = (float*)(smem + 512);  // [4][256]

    const int t    = threadIdx.x;
    const int lane = t & 63;
    const int w    = t >> 6;
    const int gb   = blockIdx.x;
    const int row0 = gb * BM;
    const int l15  = lane & 15;
    const int lg   = lane >> 4;

    const float* kb0 = key + (size_t)(row0 + w * 32 + l15) * Dn + lg * 8;
    const float* kb1 = kb0 + 16 * Dn;

    f32x4 acc[2][NJ];
    #pragma unroll
    for (int rf = 0; rf < 2; ++rf)
        #pragma unroll
        for (int j = 0; j < NJ; ++j) acc[rf][j] = (f32x4){0.f, 0.f, 0.f, 0.f};

    short8 ahk[2][8];   // kept bf16-hi A fragments (phase 2 source)
    float4 kv[2][4];    // current quarter's key (2 k-steps)

    // prologue: key quarter 0 + B quarter 0 into buf0
    #pragma unroll
    for (int ks2 = 0; ks2 < 2; ++ks2) {
        kv[0][ks2 * 2]     = *(const float4*)(kb0 + ks2 * 32);
        kv[0][ks2 * 2 + 1] = *(const float4*)(kb0 + ks2 * 32 + 4);
        kv[1][ks2 * 2]     = *(const float4*)(kb1 + ks2 * 32);
        kv[1][ks2 * 2 + 1] = *(const float4*)(kb1 + ks2 * 32 + 4);
    }
    #pragma unroll
    for (int i = 0; i < 8; ++i) {
        int c   = i * 256 + t;
        int cl  = c & 63;
        int cs  = (c >> 6) & 1;
        int cj  = (c >> 7) & 7;
        int ck2 = (c >> 10) & 1;
        int g   = ck2 * 8 + cj;
        const ushort* src = (cs ? Blo : Bhi) + ((size_t)g * 64 + cl) * 8;
        gload_lds16(src, smem + (i * 256 + w * 64) * 16);
    }
    __syncthreads();

    process_quarter<0>(smem, kb0, kb1, Bhi, Blo, t, w, lane, kv, ahk, acc);
    process_quarter<1>(smem, kb0, kb1, Bhi, Blo, t, w, lane, kv, ahk, acc);
    process_quarter<2>(smem, kb0, kb1, Bhi, Blo, t, w, lane, kv, ahk, acc);
    process_quarter<3>(smem, kb0, kb1, Bhi, Blo, t, w, lane, kv, ahk, acc);

    // Epilogue: s(row) = sum_col tanh(acc+bias)*u; e = exp(s)*mask.
    // C/D layout: col = 16j + l15, row(frag-local) = lg*4 + reg.
    #pragma unroll
    for (int rf = 0; rf < 2; ++rf) {
        float s4[4] = {0.f, 0.f, 0.f, 0.f};
        #pragma unroll
        for (int j = 0; j < NJ; ++j) {
            int col = j * 16 + l15;
            float bv = bias[col], uvv = u[col];
            #pragma unroll
            for (int reg = 0; reg < 4; ++reg)
                s4[reg] += tanh_fast(acc[rf][j][reg] + bv) * uvv;
        }
        #pragma unroll
        for (int reg = 0; reg < 4; ++reg) {
            float s = s4[reg];
            s += __shfl_xor(s, 1);
            s += __shfl_xor(s, 2);
            s += __shfl_xor(s, 4);
            s += __shfl_xor(s, 8);
            if (l15 == 0) {
                int rl = w * 32 + rf * 16 + lg * 4 + reg;
                es[rl] = __builtin_amdgcn_exp2f(s * 1.4426950408889634f)
                         * (float)mask[row0 + rl];
            }
        }
    }
    __syncthreads();

    // block-partial denominator
    if (t < 64) {
        float v = es[t] + es[t + 64];
        #pragma unroll
        for (int m = 1; m < 64; m <<= 1) v += __shfl_xor(v, m);
        if (t == 0) den[gb] = v;
    }

    // phase 2 from registers: P[d] = sum_rows e(row) * key_hi(row, d).
    // Lane (l15,lg) holds rows {w*32+l15, +16} for d = ks*32 + lg*8 + i.
    {
        float e0 = es[w * 32 + l15];
        float e1 = es[w * 32 + l15 + 16];
        #pragma unroll
        for (int ks = 0; ks < 8; ++ks) {
            float p[8];
            #pragma unroll
            for (int i = 0; i < 8; ++i)
                p[i] = e0 * hi2f(ahk[0][ks][i]) + e1 * hi2f(ahk[1][ks][i]);
            #pragma unroll
            for (int i = 0; i < 8; ++i) {
                p[i] += __shfl_xor(p[i], 1);
                p[i] += __shfl_xor(p[i], 2);
                p[i] += __shfl_xor(p[i], 4);
                p[i] += __shfl_xor(p[i], 8);
            }
            if (l15 == 0) {
                float* dst = &part[w * 256 + ks * 32 + lg * 8];
                *(float4*)(dst)     = make_float4(p[0], p[1], p[2], p[3]);
                *(float4*)(dst + 4) = make_float4(p[4], p[5], p[6], p[7]);
            }
        }
    }
    __syncthreads();

    if (t < 64) {
        float4 o = *(float4*)&part[t * 4];
        #pragma unroll
        for (int wv = 1; wv < 4; ++wv) {
            float4 pv = *(float4*)&part[wv * 256 + t * 4];
            o.x += pv.x; o.y += pv.y; o.z += pv.z; o.w += pv.w;
        }
        *(float4*)(P + (size_t)gb * Dn + t * 4) = o;
    }
}

// combine 8 block-partials per batch, normalize.
__global__ __launch_bounds__(256) void k_final(const float* __restrict__ P,
        const float* __restrict__ den, float* __restrict__ out) {
    int b = blockIdx.x, t = threadIdx.x;
    float dtot = 0.f;
    #pragma unroll
    for (int k = 0; k < 8; ++k) dtot += den[b * 8 + k];
    float o = 0.f;
    #pragma unroll
    for (int k = 0; k < 8; ++k) o += P[(size_t)(b * 8 + k) * Dn + t];
    out[(size_t)b * Dn + t] = o / (dtot + EPS_F);
}

extern "C" void kernel_launch(void* const* d_in, const int* in_sizes, int n_in,
                              void* d_out, int out_size, void* d_ws, size_t ws_size,
                              hipStream_t stream) {
    const float* key   = (const float*)d_in[0];
    const float* query = (const float*)d_in[1];
    const int*   mask  = (const int*)d_in[2];
    const float* W     = (const float*)d_in[3];
    const float* bias  = (const float*)d_in[4];
    const float* Wu    = (const float*)d_in[5];
    float* out = (float*)d_out;

    char* ws = (char*)d_ws;
    float*  u   = (float*)(ws);
    ushort* Bhi = (ushort*)(ws + 512);
    ushort* Blo = (ushort*)(ws + 66048);
    float*  Pp  = (float*)(ws + 131584);
    float*  den = (float*)(ws + 1180160);

    hipLaunchKernelGGL(k_prep,   dim3(17),   dim3(256), 0, stream, Wu, query, u, W, Bhi, Blo);
    hipLaunchKernelGGL(k_scores, dim3(NBLK), dim3(256), 0, stream,
                       key, Bhi, Blo, bias, u, mask, Pp, den);
    hipLaunchKernelGGL(k_final,  dim3(Bn),   dim3(256), 0, stream, Pp, den, out);
}

// Round 9
// 55.710 us; speedup vs baseline: 1.4409x; 1.0677x over previous
//
#include <hip/hip_runtime.h>
#include <hip/hip_bf16.h>
#include <math.h>

#define EPS_F 1e-7f

constexpr int Bn = 128, Sn = 1024, Dn = 256, ATTn = 128, QDn = 128;
constexpr int Mn = Bn * Sn;          // 131072 rows
constexpr int BM = 128;              // rows per block (8 waves x 16 rows)
constexpr int NBLK = Mn / BM;        // 1024 blocks
constexpr int NJ = ATTn / 16;        // 8 column fragments

typedef short short8 __attribute__((ext_vector_type(8)));
typedef float f32x4  __attribute__((ext_vector_type(4)));

// Exact truncation split: f = hi + r exactly (hi = top-16-bit float),
// lo = bf16_rne(r). A_hi*B_hi + A_hi*B_lo + A_lo*B_hi ~ 2^-17 relative.
__device__ inline void split_bf(float f, ushort& hi, ushort& lo) {
    uint fb = __float_as_uint(f);
    hi = (ushort)(fb >> 16);
    float hf = __uint_as_float(fb & 0xffff0000u);
    float lf = f - hf;                       // exact
    __hip_bfloat16 lb = __float2bfloat16(lf);
    __builtin_memcpy(&lo, &lb, 2);
}

__device__ inline float tanh_fast(float x) {
    float cx = fminf(9.0f, fmaxf(-9.0f, x));
    float e = __builtin_amdgcn_exp2f(cx * 2.8853900817779268f);  // e^{2x}
    return (e - 1.0f) * __builtin_amdgcn_rcpf(e + 1.0f);
}

// async global->LDS, 16B per lane. LDS dest is wave-uniform base + lane*16.
__device__ inline void gload_lds16(const void* g, void* lds_base) {
    __builtin_amdgcn_global_load_lds(
        (const __attribute__((address_space(1))) unsigned int*)g,
        (__attribute__((address_space(3))) unsigned int*)lds_base, 16, 0, 0);
}

#define MFMA_BF16 __builtin_amdgcn_mfma_f32_16x16x32_bf16

// ---------------- ws layout (bytes) ----------------
// [0,512)              u (128 f32)
// [512,66048)          Bhi (8ks * 8j * 64lane * 8 bf16)
// [66048,131584)       Blo
// [131584,1180160)     P   (1024 blk * 256 d f32)
// [1180160,1184256)    den (1024 f32)

// Merged prep: block 0 computes u = W_u @ query; blocks 1..16 build the
// MFMA-B-fragment-ordered bf16 hi/lo copies of W.
// Fragment (ks,j): lane l holds col = 16j+(l&15), k = 32ks+(l>>4)*8+i.
__global__ __launch_bounds__(256) void k_prep(
    const float* __restrict__ Wu, const float* __restrict__ q,
    float* __restrict__ u,
    const float* __restrict__ W,
    ushort* __restrict__ Bhi, ushort* __restrict__ Blo)
{
    if (blockIdx.x == 0) {
        __shared__ float qs[QDn];
        int t = threadIdx.x;
        if (t < QDn) qs[t] = q[t];
        __syncthreads();
        if (t < ATTn) {
            float acc = 0.f;
            #pragma unroll 8
            for (int j = 0; j < QDn; ++j) acc += Wu[t * QDn + j] * qs[j];
            u[t] = acc;
        }
        return;
    }
    int gid  = (blockIdx.x - 1) * 256 + threadIdx.x;   // 0..4095
    int lane = gid & 63;
    int j    = (gid >> 6) & 7;
    int ks   = gid >> 9;
    int col  = j * 16 + (lane & 15);
    int kb   = ks * 32 + (lane >> 4) * 8;
    #pragma unroll
    for (int i = 0; i < 8; ++i) {
        float f = W[(size_t)(kb + i) * ATTn + col];
        ushort h, l;
        split_bf(f, h, l);
        size_t idx = (size_t)gid * 8 + i;
        Bhi[idx] = h; Blo[idx] = l;
    }
}

// Stage one K-half of B (hi||lo, 64 KB) into LDS. Linear copy:
// slot c = i*512 + t; c<2048 -> Bhi chunk h*2048+c, else Blo chunk h*2048+c-2048.
__device__ __forceinline__ void stage_half(
    float4* smem, const ushort* __restrict__ Bhi,
    const ushort* __restrict__ Blo, int h, int t) {
    const int w = t >> 6;
    #pragma unroll
    for (int i = 0; i < 8; ++i) {
        int c  = i * 512 + t;
        int hp = c >> 11;               // wave-uniform (64-aligned ranges)
        int c2 = c & 2047;
        const ushort* src = (hp ? Blo : Bhi) + ((size_t)(h * 2048 + c2)) * 8;
        gload_lds16(src, smem + (i * 512 + w * 64));
    }
}

// One k-step (K=32): convert kv -> bf16 hi/lo, refill kv 2 ahead,
// 8 column fragments x 3 split-MFMAs with j+1 LDS prefetch.
template<int KS>
__device__ __forceinline__ void kstep(
    const float4* smem, const float* kb,
    float4 (&kv)[2][2], f32x4 (&acc)[NJ], int lane)
{
    constexpr int S = KS & 1, KSL = KS & 3;
    short8 ah, al;
    {
        float4 v0 = kv[S][0], v1 = kv[S][1];
        float f[8] = {v0.x, v0.y, v0.z, v0.w, v1.x, v1.y, v1.z, v1.w};
        #pragma unroll
        for (int i = 0; i < 8; ++i) {
            ushort h, l;
            split_bf(f[i], h, l);
            ah[i] = (short)h; al[i] = (short)l;
        }
    }
    if (KS + 2 < 8) {   // counted-vmcnt prefetch, 2 k-steps ahead
        kv[S][0] = *(const float4*)(kb + (KS + 2) * 32);
        kv[S][1] = *(const float4*)(kb + (KS + 2) * 32 + 4);
    }
    const float4* Bh = smem + KSL * 512 + lane;
    const float4* Bl = smem + 2048 + KSL * 512 + lane;
    short8 bh = *(const short8*)Bh;
    short8 bl = *(const short8*)Bl;
    #pragma unroll
    for (int j = 0; j < NJ; ++j) {
        short8 nbh, nbl;
        if (j + 1 < NJ) {
            nbh = *(const short8*)(Bh + (j + 1) * 64);
            nbl = *(const short8*)(Bl + (j + 1) * 64);
        }
        acc[j] = MFMA_BF16(ah, bh, acc[j], 0, 0, 0);
        acc[j] = MFMA_BF16(ah, bl, acc[j], 0, 0, 0);
        acc[j] = MFMA_BF16(al, bh, acc[j], 0, 0, 0);
        bh = nbh; bl = nbl;
    }
}

// Fused: scores (bf16-split MFMA, K=256, N=128) + partial weighted sums.
// 8 waves x 16 rows; B K-half resident in 64 KB LDS (restaged once);
// the two 4-k-step bursts run with NO barriers (counted waits only).
__global__ __launch_bounds__(512, 4) void k_scores(
    const float*  __restrict__ key,
    const ushort* __restrict__ Bhi, const ushort* __restrict__ Blo,
    const float*  __restrict__ bias, const float* __restrict__ u,
    const int*    __restrict__ mask,
    float* __restrict__ P, float* __restrict__ den)
{
    __shared__ float4 smem[4096];        // 64 KB: B half; aliased es/part after
    float*  esp   = (float*)smem;        // [128] scores (B dead by then)
    float4* partp = smem + 256;          // [8][64] float4 partials

    const int t    = threadIdx.x;        // 0..511
    const int lane = t & 63;
    const int w    = t >> 6;             // wave 0..7 -> rows w*16..w*16+15
    const int gb   = blockIdx.x;
    const int row0 = gb * BM;
    const int l15  = lane & 15;
    const int lg   = lane >> 4;

    const float* kb = key + (size_t)(row0 + w * 16 + l15) * Dn + lg * 8;

    f32x4 acc[NJ];
    #pragma unroll
    for (int j = 0; j < NJ; ++j) acc[j] = (f32x4){0.f, 0.f, 0.f, 0.f};

    float4 kv[2][2];
    kv[0][0] = *(const float4*)(kb);
    kv[0][1] = *(const float4*)(kb + 4);
    kv[1][0] = *(const float4*)(kb + 32);
    kv[1][1] = *(const float4*)(kb + 36);

    stage_half(smem, Bhi, Blo, 0, t);
    __syncthreads();

    kstep<0>(smem, kb, kv, acc, lane);
    kstep<1>(smem, kb, kv, acc, lane);
    kstep<2>(smem, kb, kv, acc, lane);
    kstep<3>(smem, kb, kv, acc, lane);
    __syncthreads();                     // all waves done reading half 0
    stage_half(smem, Bhi, Blo, 1, t);
    __syncthreads();                     // half 1 landed
    kstep<4>(smem, kb, kv, acc, lane);
    kstep<5>(smem, kb, kv, acc, lane);
    kstep<6>(smem, kb, kv, acc, lane);
    kstep<7>(smem, kb, kv, acc, lane);
    __syncthreads();                     // B dead; smem can be reused

    // Epilogue: s(row) = sum_col tanh(acc+bias)*u; e = exp(s)*mask.
    // C/D layout: col = 16j + l15, row(frag-local) = lg*4 + reg.
    float s4[4] = {0.f, 0.f, 0.f, 0.f};
    #pragma unroll
    for (int j = 0; j < NJ; ++j) {
        int col = j * 16 + l15;
        float bv = bias[col], uvv = u[col];
        #pragma unroll
        for (int reg = 0; reg < 4; ++reg)
            s4[reg] += tanh_fast(acc[j][reg] + bv) * uvv;
    }
    #pragma unroll
    for (int reg = 0; reg < 4; ++reg) {
        float s = s4[reg];
        s += __shfl_xor(s, 1);
        s += __shfl_xor(s, 2);
        s += __shfl_xor(s, 4);
        s += __shfl_xor(s, 8);
        if (l15 == 0) {
            int rl = w * 16 + lg * 4 + reg;
            esp[rl] = __builtin_amdgcn_exp2f(s * 1.4426950408889634f)
                      * (float)mask[row0 + rl];
        }
    }
    __syncthreads();

    // block-partial denominator
    if (t < 64) {
        float v = esp[t] + esp[t + 64];
        #pragma unroll
        for (int m = 1; m < 64; m <<= 1) v += __shfl_xor(v, m);
        if (t == 0) den[gb] = v;
    }

    // phase 2: wave w sums its 16 rows over all d (tile is L2/L3-hot).
    {
        const float4* kt = (const float4*)(key + (size_t)(row0 + w * 16) * Dn);
        float4 a2 = make_float4(0.f, 0.f, 0.f, 0.f);
        #pragma unroll 4
        for (int s2 = 0; s2 < 16; ++s2) {
            float wv  = esp[w * 16 + s2];
            float4 kvv = kt[(size_t)s2 * 64 + lane];
            a2.x += wv * kvv.x; a2.y += wv * kvv.y;
            a2.z += wv * kvv.z; a2.w += wv * kvv.w;
        }
        partp[w * 64 + lane] = a2;
    }
    __syncthreads();

    if (t < 64) {
        float4 o = partp[t];
        #pragma unroll
        for (int wv = 1; wv < 8; ++wv) {
            float4 p = partp[wv * 64 + t];
            o.x += p.x; o.y += p.y; o.z += p.z; o.w += p.w;
        }
        *(float4*)(P + (size_t)gb * Dn + t * 4) = o;
    }
}

// combine 8 block-partials per batch, normalize.
__global__ __launch_bounds__(256) void k_final(const float* __restrict__ P,
        const float* __restrict__ den, float* __restrict__ out) {
    int b = blockIdx.x, t = threadIdx.x;
    float dtot = 0.f;
    #pragma unroll
    for (int k = 0; k < 8; ++k) dtot += den[b * 8 + k];
    float o = 0.f;
    #pragma unroll
    for (int k = 0; k < 8; ++k) o += P[(size_t)(b * 8 + k) * Dn + t];
    out[(size_t)b * Dn + t] = o / (dtot + EPS_F);
}

extern "C" void kernel_launch(void* const* d_in, const int* in_sizes, int n_in,
                              void* d_out, int out_size, void* d_ws, size_t ws_size,
                              hipStream_t stream) {
    const float* key   = (const float*)d_in[0];
    const float* query = (const float*)d_in[1];
    const int*   mask  = (const int*)d_in[2];
    const float* W     = (const float*)d_in[3];
    const float* bias  = (const float*)d_in[4];
    const float* Wu    = (const float*)d_in[5];
    float* out = (float*)d_out;

    char* ws = (char*)d_ws;
    float*  u   = (float*)(ws);
    ushort* Bhi = (ushort*)(ws + 512);
    ushort* Blo = (ushort*)(ws + 66048);
    float*  Pp  = (float*)(ws + 131584);
    float*  den = (float*)(ws + 1180160);

    hipLaunchKernelGGL(k_prep,   dim3(17),   dim3(256), 0, stream, Wu, query, u, W, Bhi, Blo);
    hipLaunchKernelGGL(k_scores, dim3(NBLK), dim3(512), 0, stream,
                       key, Bhi, Blo, bias, u, mask, Pp, den);
    hipLaunchKernelGGL(k_final,  dim3(Bn),   dim3(256), 0, stream, Pp, den, out);
}